// Round 3
// baseline (171.623 us; speedup 1.0000x reference)
//
#include <hip/hip_runtime.h>
#include <hip/hip_bf16.h>

// Problem constants
#define BB 16
#define SS 128
#define DD 128
#define EE 64
#define TT 128
#define NN (BB*SS)      // 2048 tokens
#define KSPLIT 16       // K split for the big GEMM (d-chunks of 8)

typedef __attribute__((ext_vector_type(8))) short short8;
typedef __attribute__((ext_vector_type(4))) float f32x4;
typedef __attribute__((ext_vector_type(4))) unsigned int u32x4;

__device__ inline unsigned pkbf16(float a, float b) {
    unsigned r;
    asm volatile("v_cvt_pk_bf16_f32 %0, %1, %2" : "=v"(r) : "v"(a), "v"(b));
    return r;
}
__device__ inline float bflo(unsigned u) { return __builtin_bit_cast(float, (unsigned)(u << 16)); }
__device__ inline float bfhi(unsigned u) { return __builtin_bit_cast(float, (unsigned)(u & 0xffff0000u)); }

// ---------------- prep: c_bg, base ----------------
__global__ void k_basics(const float* __restrict__ b2, const float* __restrict__ wr,
                         const float* __restrict__ br, float* __restrict__ basics) {
    __shared__ float red[128];
    int t = threadIdx.x;
    red[t] = wr[t];
    __syncthreads();
    for (int s = 64; s > 0; s >>= 1) {
        if (t < s) red[t] += red[t + s];
        __syncthreads();
    }
    float swr = red[0];
    float cbg = tanhf(b2[t]);
    basics[t] = cbg;                    // c_bg[p]
    basics[128 + t] = swr * cbg + br[0]; // base[p]
}

// ---------------- prep: G1[v][t][d] = sum_e W1[t][d][e]*dep_table[v][e] (bf16) ----------------
__global__ void k_g1(const float* __restrict__ W1, const float* __restrict__ dep_table,
                     __hip_bfloat16* __restrict__ G1) {
    int td = blockIdx.x * 256 + threadIdx.x;  // t*128 + d
    const float* w1row = W1 + (size_t)td * 64;
    float w1r[64];
#pragma unroll
    for (int e4 = 0; e4 < 16; e4++) {
        f32x4 v = *(const f32x4*)(w1row + e4 * 4);
        w1r[e4 * 4 + 0] = v[0]; w1r[e4 * 4 + 1] = v[1];
        w1r[e4 * 4 + 2] = v[2]; w1r[e4 * 4 + 3] = v[3];
    }
    for (int v = 0; v < 64; v++) {
        float acc = 0.f;
#pragma unroll
        for (int e = 0; e < 64; e++) acc += w1r[e] * dep_table[v * 64 + e]; // uniform -> s_load
        G1[(size_t)v * (TT * DD) + td] = __float2bfloat16(acc);
    }
}

// ---------------- prep: W2b swizzled bf16: per d, [p=128][256B row], slot s holds t-range (s^(p&7)) ----------------
__global__ void k_w2b(const float* __restrict__ W2, __hip_bfloat16* __restrict__ W2b) {
    int cid = blockIdx.x * 256 + threadIdx.x;  // 128*128*16 = 262144 chunks of 16B
    int d = cid >> 11;
    int rem = cid & 2047;
    int p = rem >> 4;
    int sp = rem & 15;
    int h = sp >> 3, s = sp & 7;
    int t0 = h * 64 + ((s ^ (p & 7))) * 8;
    const float* src = W2 + ((size_t)p * 128 + d) * 128 + t0;  // W2[p][d][t], t contiguous
    f32x4 a = *(const f32x4*)(src);
    f32x4 b = *(const f32x4*)(src + 4);
    u32x4 out;
    out[0] = pkbf16(a[0], a[1]);
    out[1] = pkbf16(a[2], a[3]);
    out[2] = pkbf16(b[0], b[1]);
    out[3] = pkbf16(b[2], b[3]);
    *(u32x4*)((char*)W2b + (size_t)cid * 16) = out;
}

// ---------------- gather tok ----------------
__global__ void k_gather(const float* __restrict__ table, const int* __restrict__ tokens,
                         float* __restrict__ tok) {
    int gid = blockIdx.x * 256 + threadIdx.x;  // 2048*128
    int n = gid >> 7, dcol = gid & 127;
    tok[gid] = table[(size_t)tokens[n] * 128 + dcol];
}

// ---------------- tde[n][t] = tanh(sum_d tok[n][d]*G1[v][t][d] + b1[t]) ----------------
__global__ void k_tde(const float* __restrict__ tok, const int* __restrict__ dep_types,
                      const float* __restrict__ b1, const __hip_bfloat16* __restrict__ G1,
                      float* __restrict__ tde) {
    int n = blockIdx.x;
    int t = threadIdx.x;  // 128
    int v = dep_types[n];
    const float* trow = tok + (size_t)n * 128;  // uniform row -> scalar loads
    const unsigned* g = (const unsigned*)(G1 + (size_t)v * (TT * DD) + t * 128);
    float acc = b1[t];
#pragma unroll
    for (int i = 0; i < 16; i++) {
        u32x4 w = *(const u32x4*)(g + i * 4);
        acc += trow[i * 8 + 0] * bflo(w[0]) + trow[i * 8 + 1] * bfhi(w[0]);
        acc += trow[i * 8 + 2] * bflo(w[1]) + trow[i * 8 + 3] * bfhi(w[1]);
        acc += trow[i * 8 + 4] * bflo(w[2]) + trow[i * 8 + 5] * bfhi(w[2]);
        acc += trow[i * 8 + 6] * bflo(w[3]) + trow[i * 8 + 7] * bfhi(w[3]);
    }
    tde[(size_t)n * 128 + t] = tanhf(acc);
}

// ---------------- big GEMM: part[ks][n][p] = sum_{d in chunk, t} tok[n][d]*tde[n][t]*W2[p][d][t] ----------------
#define LDS_SWZ(row, bcol) ((row) * 256 + ((bcol) ^ (((row) & 7) << 4)))

__global__ __launch_bounds__(256) void k_gemm(const float* __restrict__ tok,
                                              const float* __restrict__ tde,
                                              const __hip_bfloat16* __restrict__ W2b,
                                              float* __restrict__ part) {
    __shared__ char As[32768];  // A tile [n=128][k=128t] bf16, swizzled
    __shared__ char Bs[32768];  // B tile [p=128][k=128t] bf16, swizzled (matches W2b layout)
    int nb = blockIdx.x, ks = blockIdx.y;
    int tid = threadIdx.x;
    int lane = tid & 63, w = tid >> 6;
    int wm = w >> 1, wp = w & 1;
    int n0 = nb * 128, d0 = ks * 8;
    int lrow = lane & 15, lk = lane >> 4;
    int r = tid >> 1, hh = tid & 1;  // A staging: thread -> (row, 128B-half)

    f32x4 acc[4][4] = {};

    for (int dd = 0; dd < 8; dd++) {
        int d = d0 + dd;
        // stage B: linear copy of pre-swizzled 32KB block
        const char* bsrc = (const char*)W2b + (size_t)d * 32768;
#pragma unroll
        for (int i = 0; i < 8; i++) {
            int off = (i * 256 + tid) * 16;
            *(u32x4*)(Bs + off) = *(const u32x4*)(bsrc + off);
        }
        // stage A: products tok[n][d]*tde[n][t]
        float tokv = tok[(size_t)(n0 + r) * 128 + d];
        const float* trow = tde + (size_t)(n0 + r) * 128 + hh * 64;
#pragma unroll
        for (int s = 0; s < 8; s++) {
            f32x4 x = *(const f32x4*)(trow + s * 8);
            f32x4 y = *(const f32x4*)(trow + s * 8 + 4);
            u32x4 val;
            val[0] = pkbf16(x[0] * tokv, x[1] * tokv);
            val[1] = pkbf16(x[2] * tokv, x[3] * tokv);
            val[2] = pkbf16(y[0] * tokv, y[1] * tokv);
            val[3] = pkbf16(y[2] * tokv, y[3] * tokv);
            int bcol = hh * 128 + s * 16;
            *(u32x4*)(As + LDS_SWZ(r, bcol)) = val;
        }
        __syncthreads();
        // MFMA over 4 k-slices of 32
#pragma unroll
        for (int kk = 0; kk < 4; kk++) {
            short8 aF[4], bF[4];
#pragma unroll
            for (int mi = 0; mi < 4; mi++) {
                int row = wm * 64 + mi * 16 + lrow;
                aF[mi] = *(const short8*)(As + LDS_SWZ(row, kk * 64 + lk * 16));
            }
#pragma unroll
            for (int pj = 0; pj < 4; pj++) {
                int row = wp * 64 + pj * 16 + lrow;
                bF[pj] = *(const short8*)(Bs + LDS_SWZ(row, kk * 64 + lk * 16));
            }
#pragma unroll
            for (int mi = 0; mi < 4; mi++)
#pragma unroll
                for (int pj = 0; pj < 4; pj++)
                    acc[mi][pj] = __builtin_amdgcn_mfma_f32_16x16x32_bf16(
                        aF[mi], bF[pj], acc[mi][pj], 0, 0, 0);
        }
        __syncthreads();
    }
    // write fp32 partials
    float* pout = part + (size_t)ks * NN * 128;
#pragma unroll
    for (int mi = 0; mi < 4; mi++)
#pragma unroll
        for (int pj = 0; pj < 4; pj++)
#pragma unroll
            for (int rr = 0; rr < 4; rr++) {
                int row = wm * 64 + mi * 16 + (lane >> 4) * 4 + rr;
                int col = wp * 64 + pj * 16 + (lane & 15);
                pout[(size_t)(n0 + row) * 128 + col] = acc[mi][pj][rr];
            }
}

// ---------------- epilogue 1: reduce partials, tanh, delta = wr[j]*(c_nz - c_bg) ----------------
__global__ void k_e1(const float* __restrict__ part, const float* __restrict__ b2,
                     const float* __restrict__ wr, const float* __restrict__ basics,
                     float* __restrict__ delta) {
    int gid = blockIdx.x * 256 + threadIdx.x;  // 2048*128
    int p = gid & 127;
    int n = gid >> 7;
    float s = 0.f;
#pragma unroll
    for (int k = 0; k < KSPLIT; k++) s += part[(size_t)k * NN * 128 + gid];
    float c = tanhf(s + b2[p]);
    delta[gid] = wr[n & 127] * (c - basics[p]);
}

// ---------------- epilogue 2: scatter by heads; optionally apply final root mask ----------------
__global__ void k_e2(const float* __restrict__ delta, const int* __restrict__ heads,
                     const float* __restrict__ basics, float* __restrict__ outp, int final_mask) {
    int bi = blockIdx.x;  // b*128 + i
    int b = bi >> 7, i = bi & 127;
    int p = threadIdx.x;  // 128
    __shared__ int hs[128];
    hs[p] = heads[b * 128 + p];
    __syncthreads();
    float acc = basics[128 + p];  // base[p]
    for (int j = 0; j < 128; j++) {
        if (hs[j] == i) acc += delta[(size_t)(b * 128 + j) * 128 + p];
    }
    if (final_mask) {
        outp[(size_t)bi * 128 + p] = (hs[i] == 0) ? acc : 0.f;
    } else {
        outp[(size_t)bi * 128 + p] = acc;
    }
}

extern "C" void kernel_launch(void* const* d_in, const int* in_sizes, int n_in,
                              void* d_out, int out_size, void* d_ws, size_t ws_size,
                              hipStream_t stream) {
    const float* token_table = (const float*)d_in[0];
    const float* dep_table   = (const float*)d_in[1];
    const float* W1          = (const float*)d_in[2];
    const float* b1          = (const float*)d_in[3];
    const float* W2          = (const float*)d_in[4];
    const float* b2          = (const float*)d_in[5];
    const float* wr          = (const float*)d_in[6];
    const float* br          = (const float*)d_in[7];
    const int* tokens        = (const int*)d_in[8];
    const int* dep_types     = (const int*)d_in[9];
    const int* dep_heads     = (const int*)d_in[10];
    float* out = (float*)d_out;

    char* ws = (char*)d_ws;
    __hip_bfloat16* G1  = (__hip_bfloat16*)(ws);                      // 2 MB
    __hip_bfloat16* W2b = (__hip_bfloat16*)(ws + (2ull << 20));       // 4 MB
    float* tok    = (float*)(ws + (6ull << 20));                      // 1 MB
    float* tde    = (float*)(ws + (7ull << 20));                      // 1 MB
    float* delta  = (float*)(ws + (8ull << 20));                      // 1 MB
    float* part   = (float*)(ws + (9ull << 20));                      // 16 MB
    float* basics = (float*)(ws + (25ull << 20));                     // 1 KB

    k_basics<<<1, 128, 0, stream>>>(b2, wr, br, basics);
    k_g1<<<64, 256, 0, stream>>>(W1, dep_table, G1);
    k_w2b<<<1024, 256, 0, stream>>>(W2, W2b);
    k_gather<<<1024, 256, 0, stream>>>(token_table, tokens, tok);

    for (int depth = 0; depth < 2; depth++) {
        k_tde<<<NN, 128, 0, stream>>>(tok, dep_types, b1, G1, tde);
        k_gemm<<<dim3(16, KSPLIT), 256, 0, stream>>>(tok, tde, W2b, part);
        k_e1<<<1024, 256, 0, stream>>>(part, b2, wr, basics, delta);
        k_e2<<<NN, 128, 0, stream>>>(delta, dep_heads, basics,
                                     (depth == 1) ? out : tok, depth == 1);
    }
}

// Round 4
// 139.757 us; speedup vs baseline: 1.2280x; 1.2280x over previous
//
#include <hip/hip_runtime.h>
#include <hip/hip_bf16.h>

// Problem constants
#define BB 16
#define SS 128
#define DD 128
#define EE 64
#define TT 128
#define NN (BB*SS)      // 2048 tokens
#define KSPLIT 16       // K split for the big GEMM (d-chunks of 8)

typedef __attribute__((ext_vector_type(8))) short short8;
typedef __attribute__((ext_vector_type(4))) float f32x4;
typedef __attribute__((ext_vector_type(4))) unsigned int u32x4;

__device__ inline unsigned pkbf16(float a, float b) {
    unsigned r;
    asm volatile("v_cvt_pk_bf16_f32 %0, %1, %2" : "=v"(r) : "v"(a), "v"(b));
    return r;
}
__device__ inline float bflo(unsigned u) { return __builtin_bit_cast(float, (unsigned)(u << 16)); }
__device__ inline float bfhi(unsigned u) { return __builtin_bit_cast(float, (unsigned)(u & 0xffff0000u)); }

// ---------------- prep: c_bg, base ----------------
__global__ void k_basics(const float* __restrict__ b2, const float* __restrict__ wr,
                         const float* __restrict__ br, float* __restrict__ basics) {
    __shared__ float red[128];
    int t = threadIdx.x;
    red[t] = wr[t];
    __syncthreads();
    for (int s = 64; s > 0; s >>= 1) {
        if (t < s) red[t] += red[t + s];
        __syncthreads();
    }
    float swr = red[0];
    float cbg = tanhf(b2[t]);
    basics[t] = cbg;                    // c_bg[p]
    basics[128 + t] = swr * cbg + br[0]; // base[p]
}

// ---------------- prep: G1[v][t][d] = sum_e W1[t][d][e]*dep_table[v][e] (bf16) ----------------
// Round-3 fix: no w1r[64] array (was spilling to scratch at VGPR=64 -> 52us).
// E tiled in chunks of 8 VGPRs, v split 4-ways across blockIdx.y with acc[16]
// static-indexed. dep_table reads are wave-uniform -> s_load (SGPR operand).
__global__ __launch_bounds__(256) void k_g1(const float* __restrict__ W1,
                                            const float* __restrict__ dep_table,
                                            __hip_bfloat16* __restrict__ G1) {
    int td = blockIdx.x * 256 + threadIdx.x;  // t*128 + d, 64 blocks in x
    int v0 = blockIdx.y * 16;                 // 4 v-chunks in y
    const float* w1row = W1 + (size_t)td * 64;
    float acc[16] = {};
#pragma unroll
    for (int e0 = 0; e0 < 64; e0 += 8) {
        f32x4 wa = *(const f32x4*)(w1row + e0);
        f32x4 wb = *(const f32x4*)(w1row + e0 + 4);
#pragma unroll
        for (int v = 0; v < 16; v++) {
            const float* dr = dep_table + (v0 + v) * 64 + e0;  // uniform -> s_load
            acc[v] += wa[0] * dr[0] + wa[1] * dr[1] + wa[2] * dr[2] + wa[3] * dr[3]
                    + wb[0] * dr[4] + wb[1] * dr[5] + wb[2] * dr[6] + wb[3] * dr[7];
        }
    }
#pragma unroll
    for (int v = 0; v < 16; v++)
        G1[(size_t)(v0 + v) * (TT * DD) + td] = __float2bfloat16(acc[v]);
}

// ---------------- prep: W2b swizzled bf16: per d, [p=128][256B row], slot s holds t-range (s^(p&7)) ----------------
__global__ void k_w2b(const float* __restrict__ W2, __hip_bfloat16* __restrict__ W2b) {
    int cid = blockIdx.x * 256 + threadIdx.x;  // 128*128*16 = 262144 chunks of 16B
    int d = cid >> 11;
    int rem = cid & 2047;
    int p = rem >> 4;
    int sp = rem & 15;
    int h = sp >> 3, s = sp & 7;
    int t0 = h * 64 + ((s ^ (p & 7))) * 8;
    const float* src = W2 + ((size_t)p * 128 + d) * 128 + t0;  // W2[p][d][t], t contiguous
    f32x4 a = *(const f32x4*)(src);
    f32x4 b = *(const f32x4*)(src + 4);
    u32x4 out;
    out[0] = pkbf16(a[0], a[1]);
    out[1] = pkbf16(a[2], a[3]);
    out[2] = pkbf16(b[0], b[1]);
    out[3] = pkbf16(b[2], b[3]);
    *(u32x4*)((char*)W2b + (size_t)cid * 16) = out;
}

// ---------------- gather tok ----------------
__global__ void k_gather(const float* __restrict__ table, const int* __restrict__ tokens,
                         float* __restrict__ tok) {
    int gid = blockIdx.x * 256 + threadIdx.x;  // 2048*128
    int n = gid >> 7, dcol = gid & 127;
    tok[gid] = table[(size_t)tokens[n] * 128 + dcol];
}

// ---------------- tde[n][t] = tanh(sum_d tok[n][d]*G1[v][t][d] + b1[t]) ----------------
__global__ void k_tde(const float* __restrict__ tok, const int* __restrict__ dep_types,
                      const float* __restrict__ b1, const __hip_bfloat16* __restrict__ G1,
                      float* __restrict__ tde) {
    int n = blockIdx.x;
    int t = threadIdx.x;  // 128
    int v = dep_types[n];
    const float* trow = tok + (size_t)n * 128;  // uniform row -> scalar loads
    const unsigned* g = (const unsigned*)(G1 + (size_t)v * (TT * DD) + t * 128);
    float acc = b1[t];
#pragma unroll
    for (int i = 0; i < 16; i++) {
        u32x4 w = *(const u32x4*)(g + i * 4);
        acc += trow[i * 8 + 0] * bflo(w[0]) + trow[i * 8 + 1] * bfhi(w[0]);
        acc += trow[i * 8 + 2] * bflo(w[1]) + trow[i * 8 + 3] * bfhi(w[1]);
        acc += trow[i * 8 + 4] * bflo(w[2]) + trow[i * 8 + 5] * bfhi(w[2]);
        acc += trow[i * 8 + 6] * bflo(w[3]) + trow[i * 8 + 7] * bfhi(w[3]);
    }
    tde[(size_t)n * 128 + t] = tanhf(acc);
}

// ---------------- big GEMM: part[ks][n][p] = sum_{d in chunk, t} tok[n][d]*tde[n][t]*W2[p][d][t] ----------------
#define LDS_SWZ(row, bcol) ((row) * 256 + ((bcol) ^ (((row) & 7) << 4)))

__global__ __launch_bounds__(256) void k_gemm(const float* __restrict__ tok,
                                              const float* __restrict__ tde,
                                              const __hip_bfloat16* __restrict__ W2b,
                                              float* __restrict__ part) {
    __shared__ char As[32768];  // A tile [n=128][k=128t] bf16, swizzled
    __shared__ char Bs[32768];  // B tile [p=128][k=128t] bf16, swizzled (matches W2b layout)
    int nb = blockIdx.x, ks = blockIdx.y;
    int tid = threadIdx.x;
    int lane = tid & 63, w = tid >> 6;
    int wm = w >> 1, wp = w & 1;
    int n0 = nb * 128, d0 = ks * 8;
    int lrow = lane & 15, lk = lane >> 4;
    int r = tid >> 1, hh = tid & 1;  // A staging: thread -> (row, 128B-half)

    f32x4 acc[4][4] = {};

    for (int dd = 0; dd < 8; dd++) {
        int d = d0 + dd;
        // stage B: linear copy of pre-swizzled 32KB block
        const char* bsrc = (const char*)W2b + (size_t)d * 32768;
#pragma unroll
        for (int i = 0; i < 8; i++) {
            int off = (i * 256 + tid) * 16;
            *(u32x4*)(Bs + off) = *(const u32x4*)(bsrc + off);
        }
        // stage A: products tok[n][d]*tde[n][t]
        float tokv = tok[(size_t)(n0 + r) * 128 + d];
        const float* trow = tde + (size_t)(n0 + r) * 128 + hh * 64;
#pragma unroll
        for (int s = 0; s < 8; s++) {
            f32x4 x = *(const f32x4*)(trow + s * 8);
            f32x4 y = *(const f32x4*)(trow + s * 8 + 4);
            u32x4 val;
            val[0] = pkbf16(x[0] * tokv, x[1] * tokv);
            val[1] = pkbf16(x[2] * tokv, x[3] * tokv);
            val[2] = pkbf16(y[0] * tokv, y[1] * tokv);
            val[3] = pkbf16(y[2] * tokv, y[3] * tokv);
            int bcol = hh * 128 + s * 16;
            *(u32x4*)(As + LDS_SWZ(r, bcol)) = val;
        }
        __syncthreads();
        // MFMA over 4 k-slices of 32
#pragma unroll
        for (int kk = 0; kk < 4; kk++) {
            short8 aF[4], bF[4];
#pragma unroll
            for (int mi = 0; mi < 4; mi++) {
                int row = wm * 64 + mi * 16 + lrow;
                aF[mi] = *(const short8*)(As + LDS_SWZ(row, kk * 64 + lk * 16));
            }
#pragma unroll
            for (int pj = 0; pj < 4; pj++) {
                int row = wp * 64 + pj * 16 + lrow;
                bF[pj] = *(const short8*)(Bs + LDS_SWZ(row, kk * 64 + lk * 16));
            }
#pragma unroll
            for (int mi = 0; mi < 4; mi++)
#pragma unroll
                for (int pj = 0; pj < 4; pj++)
                    acc[mi][pj] = __builtin_amdgcn_mfma_f32_16x16x32_bf16(
                        aF[mi], bF[pj], acc[mi][pj], 0, 0, 0);
        }
        __syncthreads();
    }
    // write fp32 partials
    float* pout = part + (size_t)ks * NN * 128;
#pragma unroll
    for (int mi = 0; mi < 4; mi++)
#pragma unroll
        for (int pj = 0; pj < 4; pj++)
#pragma unroll
            for (int rr = 0; rr < 4; rr++) {
                int row = wm * 64 + mi * 16 + (lane >> 4) * 4 + rr;
                int col = wp * 64 + pj * 16 + (lane & 15);
                pout[(size_t)(n0 + row) * 128 + col] = acc[mi][pj][rr];
            }
}

// ---------------- epilogue 1: reduce partials, tanh, delta = wr[j]*(c_nz - c_bg) ----------------
__global__ void k_e1(const float* __restrict__ part, const float* __restrict__ b2,
                     const float* __restrict__ wr, const float* __restrict__ basics,
                     float* __restrict__ delta) {
    int gid = blockIdx.x * 256 + threadIdx.x;  // 2048*128
    int p = gid & 127;
    int n = gid >> 7;
    float s = 0.f;
#pragma unroll
    for (int k = 0; k < KSPLIT; k++) s += part[(size_t)k * NN * 128 + gid];
    float c = tanhf(s + b2[p]);
    delta[gid] = wr[n & 127] * (c - basics[p]);
}

// ---------------- epilogue 2: scatter by heads; optionally apply final root mask ----------------
__global__ void k_e2(const float* __restrict__ delta, const int* __restrict__ heads,
                     const float* __restrict__ basics, float* __restrict__ outp, int final_mask) {
    int bi = blockIdx.x;  // b*128 + i
    int b = bi >> 7, i = bi & 127;
    int p = threadIdx.x;  // 128
    __shared__ int hs[128];
    hs[p] = heads[b * 128 + p];
    __syncthreads();
    float acc = basics[128 + p];  // base[p]
    for (int j = 0; j < 128; j++) {
        if (hs[j] == i) acc += delta[(size_t)(b * 128 + j) * 128 + p];
    }
    if (final_mask) {
        outp[(size_t)bi * 128 + p] = (hs[i] == 0) ? acc : 0.f;
    } else {
        outp[(size_t)bi * 128 + p] = acc;
    }
}

extern "C" void kernel_launch(void* const* d_in, const int* in_sizes, int n_in,
                              void* d_out, int out_size, void* d_ws, size_t ws_size,
                              hipStream_t stream) {
    const float* token_table = (const float*)d_in[0];
    const float* dep_table   = (const float*)d_in[1];
    const float* W1          = (const float*)d_in[2];
    const float* b1          = (const float*)d_in[3];
    const float* W2          = (const float*)d_in[4];
    const float* b2          = (const float*)d_in[5];
    const float* wr          = (const float*)d_in[6];
    const float* br          = (const float*)d_in[7];
    const int* tokens        = (const int*)d_in[8];
    const int* dep_types     = (const int*)d_in[9];
    const int* dep_heads     = (const int*)d_in[10];
    float* out = (float*)d_out;

    char* ws = (char*)d_ws;
    __hip_bfloat16* G1  = (__hip_bfloat16*)(ws);                      // 2 MB
    __hip_bfloat16* W2b = (__hip_bfloat16*)(ws + (2ull << 20));       // 4 MB
    float* tok    = (float*)(ws + (6ull << 20));                      // 1 MB
    float* tde    = (float*)(ws + (7ull << 20));                      // 1 MB
    float* delta  = (float*)(ws + (8ull << 20));                      // 1 MB
    float* part   = (float*)(ws + (9ull << 20));                      // 16 MB
    float* basics = (float*)(ws + (25ull << 20));                     // 1 KB

    k_basics<<<1, 128, 0, stream>>>(b2, wr, br, basics);
    k_g1<<<dim3(64, 4), 256, 0, stream>>>(W1, dep_table, G1);
    k_w2b<<<1024, 256, 0, stream>>>(W2, W2b);
    k_gather<<<1024, 256, 0, stream>>>(token_table, tokens, tok);

    for (int depth = 0; depth < 2; depth++) {
        k_tde<<<NN, 128, 0, stream>>>(tok, dep_types, b1, G1, tde);
        k_gemm<<<dim3(16, KSPLIT), 256, 0, stream>>>(tok, tde, W2b, part);
        k_e1<<<1024, 256, 0, stream>>>(part, b2, wr, basics, delta);
        k_e2<<<NN, 128, 0, stream>>>(delta, dep_heads, basics,
                                     (depth == 1) ? out : tok, depth == 1);
    }
}

// Round 5
// 118.989 us; speedup vs baseline: 1.4423x; 1.1745x over previous
//
#include <hip/hip_runtime.h>
#include <hip/hip_bf16.h>

// Problem constants
#define BB 16
#define SS 128
#define DD 128
#define EE 64
#define TT 128
#define NN (BB*SS)      // 2048 tokens
#define KSPLIT 16       // K split for the big GEMM (d-chunks of 8)

typedef __attribute__((ext_vector_type(8))) short short8;
typedef __attribute__((ext_vector_type(4))) float f32x4;
typedef __attribute__((ext_vector_type(4))) unsigned int u32x4;

__device__ inline unsigned pkbf16(float a, float b) {
    unsigned r;
    asm volatile("v_cvt_pk_bf16_f32 %0, %1, %2" : "=v"(r) : "v"(a), "v"(b));
    return r;
}
__device__ inline float bflo(unsigned u) { return __builtin_bit_cast(float, (unsigned)(u << 16)); }
__device__ inline float bfhi(unsigned u) { return __builtin_bit_cast(float, (unsigned)(u & 0xffff0000u)); }

// ---------------- fused prep: g1 (256 blk) + w2b (1024 blk) + gather (1024 blk) + basics (1 blk) ----------------
__global__ __launch_bounds__(256) void k_prep(const float* __restrict__ W1,
                                              const float* __restrict__ dep_table,
                                              const float* __restrict__ W2,
                                              const float* __restrict__ token_table,
                                              const int* __restrict__ tokens,
                                              const float* __restrict__ b2,
                                              const float* __restrict__ wr,
                                              const float* __restrict__ br,
                                              __hip_bfloat16* __restrict__ G1,
                                              __hip_bfloat16* __restrict__ W2b,
                                              float* __restrict__ tok,
                                              float* __restrict__ basics) {
    int bid = blockIdx.x;
    int tid = threadIdx.x;
    if (bid < 256) {
        // --- G1[v][t][d] = sum_e W1[t][d][e]*dep_table[v][e] (bf16), no spills ---
        int bx = bid & 63, by = bid >> 6;
        int td = bx * 256 + tid;      // t*128 + d
        int v0 = by * 16;             // v-chunk
        const float* w1row = W1 + (size_t)td * 64;
        float acc[16] = {};
#pragma unroll
        for (int e0 = 0; e0 < 64; e0 += 8) {
            f32x4 wa = *(const f32x4*)(w1row + e0);
            f32x4 wb = *(const f32x4*)(w1row + e0 + 4);
#pragma unroll
            for (int v = 0; v < 16; v++) {
                const float* dr = dep_table + (v0 + v) * 64 + e0;  // wave-uniform -> s_load
                acc[v] += wa[0] * dr[0] + wa[1] * dr[1] + wa[2] * dr[2] + wa[3] * dr[3]
                        + wb[0] * dr[4] + wb[1] * dr[5] + wb[2] * dr[6] + wb[3] * dr[7];
            }
        }
#pragma unroll
        for (int v = 0; v < 16; v++)
            G1[(size_t)(v0 + v) * (TT * DD) + td] = __float2bfloat16(acc[v]);
    } else if (bid < 1280) {
        // --- W2b pre-swizzled bf16: per d, [p=128][256B row], slot s holds t-range (s^(p&7)) ---
        int cid = (bid - 256) * 256 + tid;  // 262144 chunks of 16B
        int d = cid >> 11;
        int rem = cid & 2047;
        int p = rem >> 4;
        int sp = rem & 15;
        int h = sp >> 3, s = sp & 7;
        int t0 = h * 64 + ((s ^ (p & 7))) * 8;
        const float* src = W2 + ((size_t)p * 128 + d) * 128 + t0;  // W2[p][d][t]
        f32x4 a = *(const f32x4*)(src);
        f32x4 b = *(const f32x4*)(src + 4);
        u32x4 o;
        o[0] = pkbf16(a[0], a[1]);
        o[1] = pkbf16(a[2], a[3]);
        o[2] = pkbf16(b[0], b[1]);
        o[3] = pkbf16(b[2], b[3]);
        *(u32x4*)((char*)W2b + (size_t)cid * 16) = o;
    } else if (bid < 2304) {
        // --- gather tok ---
        int gid = (bid - 1280) * 256 + tid;  // 2048*128
        int n = gid >> 7, dcol = gid & 127;
        tok[gid] = token_table[(size_t)tokens[n] * 128 + dcol];
    } else {
        // --- basics: c_bg[p], base[p] (barrier-uniform across all 256 threads) ---
        __shared__ float red[128];
        int t = tid;
        if (t < 128) red[t] = wr[t];
        __syncthreads();
        for (int s = 64; s > 0; s >>= 1) {
            if (t < s) red[t] += red[t + s];
            __syncthreads();
        }
        if (t < 128) {
            float swr = red[0];
            float cbg = tanhf(b2[t]);
            basics[t] = cbg;                     // c_bg[p]
            basics[128 + t] = swr * cbg + br[0]; // base[p]
        }
    }
}

// ---------------- tde[n][t] = tanh(sum_d tok[n][d]*G1[v][t][d] + b1[t]) ----------------
__global__ void k_tde(const float* __restrict__ tok, const int* __restrict__ dep_types,
                      const float* __restrict__ b1, const __hip_bfloat16* __restrict__ G1,
                      float* __restrict__ tde) {
    int n = blockIdx.x;
    int t = threadIdx.x;  // 128
    int v = dep_types[n];
    const float* trow = tok + (size_t)n * 128;  // uniform row -> scalar loads
    const unsigned* g = (const unsigned*)(G1 + (size_t)v * (TT * DD) + t * 128);
    float acc = b1[t];
#pragma unroll
    for (int i = 0; i < 16; i++) {
        u32x4 w = *(const u32x4*)(g + i * 4);
        acc += trow[i * 8 + 0] * bflo(w[0]) + trow[i * 8 + 1] * bfhi(w[0]);
        acc += trow[i * 8 + 2] * bflo(w[1]) + trow[i * 8 + 3] * bfhi(w[1]);
        acc += trow[i * 8 + 4] * bflo(w[2]) + trow[i * 8 + 5] * bfhi(w[2]);
        acc += trow[i * 8 + 6] * bflo(w[3]) + trow[i * 8 + 7] * bfhi(w[3]);
    }
    tde[(size_t)n * 128 + t] = tanhf(acc);
}

// ---------------- big GEMM: part[ks][n][p] = sum_{d in chunk, t} tok[n][d]*tde[n][t]*W2[p][d][t] ----------------
// Round-4 change: BM 128->64 (grid 32x16=512 wg, LDS 48KB -> 2-3 wg/CU) so one
// wg's MFMA phase overlaps another's staging phase (was 1 wg/CU = hard serialization).
#define LDS_SWZ(row, bcol) ((row) * 256 + ((bcol) ^ (((row) & 7) << 4)))

__global__ __launch_bounds__(256) void k_gemm(const float* __restrict__ tok,
                                              const float* __restrict__ tde,
                                              const __hip_bfloat16* __restrict__ W2b,
                                              float* __restrict__ part) {
    __shared__ char As[16384];  // A tile [n=64][k=128t] bf16, swizzled
    __shared__ char Bs[32768];  // B tile [p=128][k=128t] bf16, swizzled (matches W2b layout)
    int nb = blockIdx.x, ks = blockIdx.y;
    int tid = threadIdx.x;
    int lane = tid & 63, w = tid >> 6;
    int wm = w >> 1, wp = w & 1;        // 2 m-warps x 2 p-warps
    int n0 = nb * 64, d0 = ks * 8;
    int lrow = lane & 15, lk = lane >> 4;
    int r = tid >> 2, q = tid & 3;      // A staging: row r (64 rows), 64B quarter q

    f32x4 acc[2][4] = {};

    for (int dd = 0; dd < 8; dd++) {
        int d = d0 + dd;
        // stage B: linear copy of pre-swizzled 32KB block
        const char* bsrc = (const char*)W2b + (size_t)d * 32768;
#pragma unroll
        for (int i = 0; i < 8; i++) {
            int off = (i * 256 + tid) * 16;
            *(u32x4*)(Bs + off) = *(const u32x4*)(bsrc + off);
        }
        // stage A: products tok[n][d]*tde[n][t], 32 t-values per thread
        float tokv = tok[(size_t)(n0 + r) * 128 + d];
        const float* trow = tde + (size_t)(n0 + r) * 128 + q * 32;
#pragma unroll
        for (int s = 0; s < 4; s++) {
            f32x4 x = *(const f32x4*)(trow + s * 8);
            f32x4 y = *(const f32x4*)(trow + s * 8 + 4);
            u32x4 val;
            val[0] = pkbf16(x[0] * tokv, x[1] * tokv);
            val[1] = pkbf16(x[2] * tokv, x[3] * tokv);
            val[2] = pkbf16(y[0] * tokv, y[1] * tokv);
            val[3] = pkbf16(y[2] * tokv, y[3] * tokv);
            int bcol = q * 64 + s * 16;
            *(u32x4*)(As + LDS_SWZ(r, bcol)) = val;
        }
        __syncthreads();
        // MFMA over 4 k-slices of 32
#pragma unroll
        for (int kk = 0; kk < 4; kk++) {
            short8 aF[2], bF[4];
#pragma unroll
            for (int mi = 0; mi < 2; mi++) {
                int row = wm * 32 + mi * 16 + lrow;
                aF[mi] = *(const short8*)(As + LDS_SWZ(row, kk * 64 + lk * 16));
            }
#pragma unroll
            for (int pj = 0; pj < 4; pj++) {
                int row = wp * 64 + pj * 16 + lrow;
                bF[pj] = *(const short8*)(Bs + LDS_SWZ(row, kk * 64 + lk * 16));
            }
#pragma unroll
            for (int mi = 0; mi < 2; mi++)
#pragma unroll
                for (int pj = 0; pj < 4; pj++)
                    acc[mi][pj] = __builtin_amdgcn_mfma_f32_16x16x32_bf16(
                        aF[mi], bF[pj], acc[mi][pj], 0, 0, 0);
        }
        __syncthreads();
    }
    // write fp32 partials
    float* pout = part + (size_t)ks * NN * 128;
#pragma unroll
    for (int mi = 0; mi < 2; mi++)
#pragma unroll
        for (int pj = 0; pj < 4; pj++)
#pragma unroll
            for (int rr = 0; rr < 4; rr++) {
                int row = wm * 32 + mi * 16 + (lane >> 4) * 4 + rr;
                int col = wp * 64 + pj * 16 + (lane & 15);
                pout[(size_t)(n0 + row) * 128 + col] = acc[mi][pj][rr];
            }
}

// ---------------- epilogue 1: reduce partials, tanh, delta = wr[j]*(c_nz - c_bg) ----------------
__global__ void k_e1(const float* __restrict__ part, const float* __restrict__ b2,
                     const float* __restrict__ wr, const float* __restrict__ basics,
                     float* __restrict__ delta) {
    int gid = blockIdx.x * 256 + threadIdx.x;  // 2048*128
    int p = gid & 127;
    int n = gid >> 7;
    float s = 0.f;
#pragma unroll
    for (int k = 0; k < KSPLIT; k++) s += part[(size_t)k * NN * 128 + gid];
    float c = tanhf(s + b2[p]);
    delta[gid] = wr[n & 127] * (c - basics[p]);
}

// ---------------- epilogue 2: scatter by heads; optionally apply final root mask ----------------
__global__ void k_e2(const float* __restrict__ delta, const int* __restrict__ heads,
                     const float* __restrict__ basics, float* __restrict__ outp, int final_mask) {
    int bi = blockIdx.x;  // b*128 + i
    int b = bi >> 7, i = bi & 127;
    int p = threadIdx.x;  // 128
    __shared__ int hs[128];
    hs[p] = heads[b * 128 + p];
    __syncthreads();
    float acc = basics[128 + p];  // base[p]
    for (int j = 0; j < 128; j++) {
        if (hs[j] == i) acc += delta[(size_t)(b * 128 + j) * 128 + p];  // uniform branch
    }
    if (final_mask) {
        outp[(size_t)bi * 128 + p] = (hs[i] == 0) ? acc : 0.f;
    } else {
        outp[(size_t)bi * 128 + p] = acc;
    }
}

extern "C" void kernel_launch(void* const* d_in, const int* in_sizes, int n_in,
                              void* d_out, int out_size, void* d_ws, size_t ws_size,
                              hipStream_t stream) {
    const float* token_table = (const float*)d_in[0];
    const float* dep_table   = (const float*)d_in[1];
    const float* W1          = (const float*)d_in[2];
    const float* b1          = (const float*)d_in[3];
    const float* W2          = (const float*)d_in[4];
    const float* b2          = (const float*)d_in[5];
    const float* wr          = (const float*)d_in[6];
    const float* br          = (const float*)d_in[7];
    const int* tokens        = (const int*)d_in[8];
    const int* dep_types     = (const int*)d_in[9];
    const int* dep_heads     = (const int*)d_in[10];
    float* out = (float*)d_out;

    char* ws = (char*)d_ws;
    __hip_bfloat16* G1  = (__hip_bfloat16*)(ws);                      // 2 MB
    __hip_bfloat16* W2b = (__hip_bfloat16*)(ws + (2ull << 20));       // 4 MB
    float* tok    = (float*)(ws + (6ull << 20));                      // 1 MB
    float* tde    = (float*)(ws + (7ull << 20));                      // 1 MB
    float* delta  = (float*)(ws + (8ull << 20));                      // 1 MB
    float* part   = (float*)(ws + (9ull << 20));                      // 16 MB
    float* basics = (float*)(ws + (25ull << 20));                     // 1 KB

    k_prep<<<2305, 256, 0, stream>>>(W1, dep_table, W2, token_table, tokens,
                                     b2, wr, br, G1, W2b, tok, basics);

    for (int depth = 0; depth < 2; depth++) {
        k_tde<<<NN, 128, 0, stream>>>(tok, dep_types, b1, G1, tde);
        k_gemm<<<dim3(32, KSPLIT), 256, 0, stream>>>(tok, tde, W2b, part);
        k_e1<<<1024, 256, 0, stream>>>(part, b2, wr, basics, delta);
        k_e2<<<NN, 128, 0, stream>>>(delta, dep_heads, basics,
                                     (depth == 1) ? out : tok, depth == 1);
    }
}